// Round 2
// baseline (313.819 us; speedup 1.0000x reference)
//
#include <hip/hip_runtime.h>
#include <hip/hip_bf16.h>
#include <stdint.h>

#define E_EDGES 262144
#define DFEAT 256
#define KDIM 512
#define NNODES 131072

typedef __attribute__((ext_vector_type(8))) short short8;
typedef __attribute__((ext_vector_type(4))) float f32x4;

static __device__ __forceinline__ unsigned short f2bf(float x) {
    unsigned u = __float_as_uint(x);
    u += 0x7fffu + ((u >> 16) & 1u);   // RNE
    return (unsigned short)(u >> 16);
}

// table [131072][256] f32 -> bf16, same layout. 8 floats/thread.
__global__ __launch_bounds__(256) void conv_table_kernel(const float* __restrict__ t,
                                                         unsigned short* __restrict__ o) {
    int idx = blockIdx.x * 256 + threadIdx.x;   // x8 floats
    float4 a = ((const float4*)t)[idx * 2];
    float4 b = ((const float4*)t)[idx * 2 + 1];
    uint4 w;
    w.x = (unsigned)f2bf(a.x) | ((unsigned)f2bf(a.y) << 16);
    w.y = (unsigned)f2bf(a.z) | ((unsigned)f2bf(a.w) << 16);
    w.z = (unsigned)f2bf(b.x) | ((unsigned)f2bf(b.y) << 16);
    w.w = (unsigned)f2bf(b.z) | ((unsigned)f2bf(b.w) << 16);
    ((uint4*)o)[idx] = w;
}

// W1 [512][256] f32 -> W1T [256][512] bf16
__global__ __launch_bounds__(256) void prep_w1t_kernel(const float* __restrict__ W1,
                                                       unsigned short* __restrict__ w1t) {
    int idx = blockIdx.x * 256 + threadIdx.x;   // 131072 total
    int k = idx >> 8;
    int n = idx & 255;
    w1t[n * KDIM + k] = f2bf(W1[idx]);
}

// ============================ fast path ============================
// 64 edges x 256 cols per block, K=512 bf16 in 4 steps of 128.
// A-tile [64][128] bf16 staged via global_load_lds (pre-swizzled source).
__global__ __launch_bounds__(256) void linkpred2_kernel(
    const unsigned short* __restrict__ tblb,
    const int* __restrict__ pos_src, const int* __restrict__ pos_dst,
    const int* __restrict__ neg_src, const int* __restrict__ neg_dst,
    const float* __restrict__ b1, const float* __restrict__ W2,
    const float* __restrict__ b2,
    const unsigned short* __restrict__ w1t,
    float* __restrict__ out) {

    __shared__ __align__(16) unsigned short As[2][64 * 128];  // 2 x 16 KB
    __shared__ int eIdx[2][64];                               // [0]=src [1]=dst
    __shared__ float wpart[4][64];

    const int tid = threadIdx.x;
    const int l = tid & 63;
    const int wv = tid >> 6;            // wave -> HID cols [wv*64, wv*64+64)
    const int m0 = blockIdx.x * 64;

    if (tid < 128) {
        int e = tid & 63;
        int m = m0 + e;
        int isdst = tid >> 6;
        int v;
        if (m0 < E_EDGES) v = isdst ? pos_dst[m] : pos_src[m];
        else { int mm = m - E_EDGES; v = isdst ? neg_dst[mm] : neg_src[mm]; }
        eIdx[isdst][e] = v;
    }

    float b1v[4], w2v[4];
#pragma unroll
    for (int j = 0; j < 4; j++) {
        int n = wv * 64 + j * 16 + (l & 15);
        b1v[j] = b1[n];
        w2v[j] = W2[n];
    }

    __syncthreads();

    // stage K-step s into As[buf]: 16 x 1KB global_load_lds (4 per wave).
    // LDS layout: row r (64 rows), 16 chunks of 16B; data chunk q stored at
    // chunk (q&8)|((q^r)&7)  => read-side 2-way max bank aliasing (free).
    // global_load_lds writes linearly, so the SOURCE address carries the
    // inverse (= same, involution) permutation.
    auto stage = [&](int buf, int s) {
#pragma unroll
        for (int jj = 0; jj < 4; ++jj) {
            int j = wv * 4 + jj;                 // 1KB chunk, wave-uniform
            int r = j * 4 + (l >> 4);            // row this lane feeds
            int qs = l & 15;                     // stored chunk at dest
            int q = (qs & 8) | ((qs ^ r) & 7);   // data chunk to fetch
            const unsigned short* g =
                tblb + (size_t)eIdx[s >> 1][r] * DFEAT + (s & 1) * 128 + q * 8;
            char* lp = (char*)(&As[buf][0]) + j * 1024;
            __builtin_amdgcn_global_load_lds(
                (const __attribute__((address_space(1))) void*)g,
                (__attribute__((address_space(3))) void*)lp, 16, 0, 0);
        }
    };

    stage(0, 0);
    __syncthreads();

    f32x4 acc[4][4];
#pragma unroll
    for (int i = 0; i < 4; i++)
#pragma unroll
        for (int j = 0; j < 4; j++)
            acc[i][j] = (f32x4){0.f, 0.f, 0.f, 0.f};

    for (int s = 0; s < 4; ++s) {
        const int cur = s & 1;
        if (s < 3) stage(cur ^ 1, s + 1);   // prefetch next tile (drained at barrier)

        const char* Ab = (const char*)(&As[cur][0]);
#pragma unroll
        for (int h = 0; h < 4; ++h) {
            short8 af[4], bf[4];
#pragma unroll
            for (int i = 0; i < 4; ++i) {
                int r = i * 16 + (l & 15);
                int q = h * 4 + (l >> 4);
                int byte = r * 256 + (((q & 8) | ((q ^ r) & 7)) << 4);
                af[i] = *(const short8*)(Ab + byte);
            }
#pragma unroll
            for (int j = 0; j < 4; ++j) {
                int col = wv * 64 + j * 16 + (l & 15);
                int koff = s * 128 + h * 32 + ((l >> 4) << 3);
                bf[j] = *(const short8*)(w1t + col * KDIM + koff);
            }
#pragma unroll
            for (int i = 0; i < 4; ++i)
#pragma unroll
                for (int j = 0; j < 4; ++j)
                    acc[i][j] = __builtin_amdgcn_mfma_f32_16x16x32_bf16(af[i], bf[j], acc[i][j], 0, 0, 0);
        }
        __syncthreads();
    }

    // fused epilogue: relu(acc + b1) dot W2 -> sigmoid; labels.
    float part[16];
#pragma unroll
    for (int i = 0; i < 4; i++) {
#pragma unroll
        for (int r = 0; r < 4; r++) {
            float p = 0.f;
#pragma unroll
            for (int j = 0; j < 4; j++) {
                float hv = acc[i][j][r] + b1v[j];
                hv = fmaxf(hv, 0.f);
                p = fmaf(hv, w2v[j], p);
            }
#pragma unroll
            for (int mk = 1; mk < 16; mk <<= 1) p += __shfl_xor(p, mk, 64);
            part[i * 4 + r] = p;
        }
    }
    if ((l & 15) == 0) {
        int g = l >> 4;
#pragma unroll
        for (int i = 0; i < 4; i++)
#pragma unroll
            for (int r = 0; r < 4; r++)
                wpart[wv][i * 16 + g * 4 + r] = part[i * 4 + r];
    }
    __syncthreads();

    if (tid < 64) {
        float x = wpart[0][tid] + wpart[1][tid] + wpart[2][tid] + wpart[3][tid] + b2[0];
        float sg = 1.0f / (1.0f + __expf(-x));
        out[(size_t)m0 + tid] = sg;
        out[(size_t)(2 * E_EDGES) + m0 + tid] = (m0 < E_EDGES) ? 1.0f : 0.0f;
    }
}

// ============================ fallback (round-1, known-good) ============================
__global__ __launch_bounds__(256) void linkpred_fb_kernel(
    const float* __restrict__ table,
    const int* __restrict__ pos_src, const int* __restrict__ pos_dst,
    const int* __restrict__ neg_src, const int* __restrict__ neg_dst,
    const float* __restrict__ b1, const float* __restrict__ W2,
    const float* __restrict__ b2,
    const unsigned short* __restrict__ w1t,
    float* __restrict__ out) {

    __shared__ __align__(16) unsigned short As[2][64 * 64];
    __shared__ int sIdx[64], dIdx[64];
    __shared__ float wpart[4][64];

    const int tid = threadIdx.x;
    const int l = tid & 63;
    const int wv = tid >> 6;
    const int m0 = blockIdx.x * 64;

    if (tid < 64) {
        int m = m0 + tid;
        int si, di;
        if (m < E_EDGES) { si = pos_src[m];            di = pos_dst[m]; }
        else             { si = neg_src[m - E_EDGES];  di = neg_dst[m - E_EDGES]; }
        sIdx[tid] = si;
        dIdx[tid] = di;
    }

    float b1v[4], w2v[4];
#pragma unroll
    for (int j = 0; j < 4; j++) {
        int n = wv * 64 + j * 16 + (l & 15);
        b1v[j] = b1[n];
        w2v[j] = W2[n];
    }

    __syncthreads();

    const int e0 = tid >> 3;
    const int q  = tid & 7;
    const int e1 = e0 + 32;

    auto pack_write = [&](int buf, int e, const float4& x, const float4& y) {
        uint4 w;
        w.x = (unsigned)f2bf(x.x) | ((unsigned)f2bf(x.y) << 16);
        w.y = (unsigned)f2bf(x.z) | ((unsigned)f2bf(x.w) << 16);
        w.z = (unsigned)f2bf(y.x) | ((unsigned)f2bf(y.y) << 16);
        w.w = (unsigned)f2bf(y.z) | ((unsigned)f2bf(y.w) << 16);
        int byte = e * 128 + q * 16;
        byte ^= (e & 7) << 4;
        *(uint4*)((char*)(&As[buf][0]) + byte) = w;
    };

    {
        const float* p0 = table + (size_t)sIdx[e0] * DFEAT + q * 8;
        const float* p1 = table + (size_t)sIdx[e1] * DFEAT + q * 8;
        float4 a0 = *(const float4*)p0, a1 = *(const float4*)(p0 + 4);
        float4 c0 = *(const float4*)p1, c1 = *(const float4*)(p1 + 4);
        pack_write(0, e0, a0, a1);
        pack_write(0, e1, c0, c1);
    }
    __syncthreads();

    f32x4 acc[4][4];
#pragma unroll
    for (int i = 0; i < 4; i++)
#pragma unroll
        for (int j = 0; j < 4; j++)
            acc[i][j] = (f32x4){0.f, 0.f, 0.f, 0.f};

    for (int s = 0; s < 8; s++) {
        float4 a0, a1, c0, c1;
        if (s < 7) {
            int sn = s + 1;
            const int* idxA = (sn < 4) ? sIdx : dIdx;
            int cb = (sn & 3) * 64 + q * 8;
            const float* p0 = table + (size_t)idxA[e0] * DFEAT + cb;
            const float* p1 = table + (size_t)idxA[e1] * DFEAT + cb;
            a0 = *(const float4*)p0; a1 = *(const float4*)(p0 + 4);
            c0 = *(const float4*)p1; c1 = *(const float4*)(p1 + 4);
        }

        const int cur = s & 1;
        const char* Abase = (const char*)(&As[cur][0]);
#pragma unroll
        for (int h = 0; h < 2; h++) {
            short8 af[4], bf[4];
#pragma unroll
            for (int i = 0; i < 4; i++) {
                int row = i * 16 + (l & 15);
                int byte = row * 128 + h * 64 + ((l >> 4) << 4);
                byte ^= (l & 7) << 4;
                af[i] = *(const short8*)(Abase + byte);
            }
#pragma unroll
            for (int j = 0; j < 4; j++) {
                int col = wv * 64 + j * 16 + (l & 15);
                int koff = s * 64 + h * 32 + ((l >> 4) << 3);
                bf[j] = *(const short8*)(w1t + col * KDIM + koff);
            }
#pragma unroll
            for (int i = 0; i < 4; i++)
#pragma unroll
                for (int j = 0; j < 4; j++)
                    acc[i][j] = __builtin_amdgcn_mfma_f32_16x16x32_bf16(af[i], bf[j], acc[i][j], 0, 0, 0);
        }

        if (s < 7) {
            pack_write((s + 1) & 1, e0, a0, a1);
            pack_write((s + 1) & 1, e1, c0, c1);
        }
        __syncthreads();
    }

    float part[16];
#pragma unroll
    for (int i = 0; i < 4; i++) {
#pragma unroll
        for (int r = 0; r < 4; r++) {
            float p = 0.f;
#pragma unroll
            for (int j = 0; j < 4; j++) {
                float hv = acc[i][j][r] + b1v[j];
                hv = fmaxf(hv, 0.f);
                p = fmaf(hv, w2v[j], p);
            }
#pragma unroll
            for (int mk = 1; mk < 16; mk <<= 1) p += __shfl_xor(p, mk, 64);
            part[i * 4 + r] = p;
        }
    }
    if ((l & 15) == 0) {
        int g = l >> 4;
#pragma unroll
        for (int i = 0; i < 4; i++)
#pragma unroll
            for (int r = 0; r < 4; r++)
                wpart[wv][i * 16 + g * 4 + r] = part[i * 4 + r];
    }
    __syncthreads();

    if (tid < 64) {
        float x = wpart[0][tid] + wpart[1][tid] + wpart[2][tid] + wpart[3][tid] + b2[0];
        float sg = 1.0f / (1.0f + __expf(-x));
        out[(size_t)m0 + tid] = sg;
        out[(size_t)(2 * E_EDGES) + m0 + tid] = (m0 < E_EDGES) ? 1.0f : 0.0f;
    }
}

extern "C" void kernel_launch(void* const* d_in, const int* in_sizes, int n_in,
                              void* d_out, int out_size, void* d_ws, size_t ws_size,
                              hipStream_t stream) {
    const float* table = (const float*)d_in[0];
    const int* ps = (const int*)d_in[1];
    const int* pd = (const int*)d_in[2];
    const int* ns = (const int*)d_in[3];
    const int* nd = (const int*)d_in[4];
    const float* W1 = (const float*)d_in[5];
    const float* b1 = (const float*)d_in[6];
    const float* W2 = (const float*)d_in[7];
    const float* b2 = (const float*)d_in[8];
    float* out = (float*)d_out;

    const size_t tbl_bytes = (size_t)NNODES * DFEAT * 2;       // 67,108,864
    const size_t w1t_bytes = (size_t)256 * KDIM * 2;           // 262,144

    if (ws_size >= tbl_bytes + w1t_bytes) {
        unsigned short* tblb = (unsigned short*)d_ws;
        unsigned short* w1t = (unsigned short*)((char*)d_ws + tbl_bytes);
        hipLaunchKernelGGL(conv_table_kernel, dim3(16384), dim3(256), 0, stream, table, tblb);
        hipLaunchKernelGGL(prep_w1t_kernel, dim3(512), dim3(256), 0, stream, W1, w1t);
        hipLaunchKernelGGL(linkpred2_kernel, dim3(8192), dim3(256), 0, stream,
                           tblb, ps, pd, ns, nd, b1, W2, b2, w1t, out);
    } else {
        unsigned short* w1t = (unsigned short*)d_ws;
        hipLaunchKernelGGL(prep_w1t_kernel, dim3(512), dim3(256), 0, stream, W1, w1t);
        hipLaunchKernelGGL(linkpred_fb_kernel, dim3(8192), dim3(256), 0, stream,
                           table, ps, pd, ns, nd, b1, W2, b2, w1t, out);
    }
}